// Round 3
// baseline (4806.772 us; speedup 1.0000x reference)
//
#include <hip/hip_runtime.h>

#define HN 48
#define WN 48
#define CIN_ 256
#define H_ 192
#define W_ 192
#define COUT_ 256

#define DOT4(a, xv, wv) a += xv.x*wv.x + xv.y*wv.y + xv.z*wv.z + xv.w*wv.w

// One workgroup (256 threads) per 4x4 window. Fully fused, ALL-fp32 pipeline:
//   A: load x window -> LDS xs[pix][c] (pad 260)
//   4 passes x 8 heads:
//     B:  qkv GEMM, 192 ch x 16 pix -> qs[0..191] (fp32)
//     B2: 5x5/pad2 avg-pool within 4x4 window -> qs[192..383]
//     C:  linear attention, 16 groups (8 direct + 8 pooled), 16 lanes/group
//         -> att[128 ch][16 pix] (fp32)
//     D:  partial proj GEMM: acc[l] += proj_w[oc][cols of this pass] * att
//   epilogue: BN + fp32 store
__global__ __launch_bounds__(256, 2)
void wmsa_fused(const float* __restrict__ x, const float* __restrict__ qkv_w,
                const float* __restrict__ proj_w, const float* __restrict__ bn_g,
                const float* __restrict__ bn_b, const float* __restrict__ bn_m,
                const float* __restrict__ bn_v, float* __restrict__ y)
{
    __shared__ __align__(16) float xs[16 * 260];   // 16,640 B
    __shared__ __align__(16) float qs[384 * 16];   // 24,576 B
    __shared__ __align__(16) float att[128 * 16];  //  8,192 B   total 49,408 B -> 3 WG/CU

    const int t = threadIdx.x;
    const int bid = blockIdx.x;
    // XCD swizzle: 8 consecutive windows -> same XCD (bid%8)
    const int win = (bid % 1152) * 8 + (bid / 1152);
    const int b = win / (HN * WN);
    const int rem = win % (HN * WN);
    const int hn = rem / WN, wn = rem % WN;
    const int h0 = hn * 4, w0 = wn * 4;

    // ---- Phase A: load x window (256 ch x 16 pix), fp32 ----
    for (int idx = t; idx < 1024; idx += 256) {
        const int c = idx >> 2, i = idx & 3;
        const size_t ea = ((size_t)(b * CIN_ + c) * H_ + (h0 + i)) * (size_t)W_ + w0;
        const float4 r = *reinterpret_cast<const float4*>(x + ea);  // 16B, aligned (w0%4==0)
        xs[(i * 4 + 0) * 260 + c] = r.x;
        xs[(i * 4 + 1) * 260 + c] = r.y;
        xs[(i * 4 + 2) * 260 + c] = r.z;
        xs[(i * 4 + 3) * 260 + c] = r.w;
    }

    const int og = t >> 4;     // 0..15
    const int pix = t & 15;    // 0..15

    float acc[16];             // proj accumulator, lives across all passes
#pragma unroll
    for (int l = 0; l < 16; ++l) acc[l] = 0.f;

    __syncthreads();

    for (int pass = 0; pass < 4; ++pass) {
        // ---- Phase B: qkv GEMM, heads [pass*8, pass*8+8) => 192 channels ----
        // Each thread: 12 channels (3 chunks of 4) x 1 pixel; 1 LDS b128 read feeds 16 FMAs.
        {
            const float* xrow = &xs[pix * 260];
            for (int k = 0; k < 3; ++k) {
                const int o0 = og * 12 + k * 4;          // local channel 0..191
                const size_t o = (size_t)(pass * 192 + o0);
                const float4* w0p = reinterpret_cast<const float4*>(qkv_w + (o + 0) * 256);
                const float4* w1p = reinterpret_cast<const float4*>(qkv_w + (o + 1) * 256);
                const float4* w2p = reinterpret_cast<const float4*>(qkv_w + (o + 2) * 256);
                const float4* w3p = reinterpret_cast<const float4*>(qkv_w + (o + 3) * 256);
                float a0 = 0.f, a1 = 0.f, a2 = 0.f, a3 = 0.f;
#pragma unroll 4
                for (int c4 = 0; c4 < 64; ++c4) {
                    const float4 xv = *reinterpret_cast<const float4*>(&xrow[c4 * 4]);
                    const float4 wv0 = w0p[c4];
                    const float4 wv1 = w1p[c4];
                    const float4 wv2 = w2p[c4];
                    const float4 wv3 = w3p[c4];
                    DOT4(a0, xv, wv0);
                    DOT4(a1, xv, wv1);
                    DOT4(a2, xv, wv2);
                    DOT4(a3, xv, wv3);
                }
                qs[(o0 + 0) * 16 + pix] = a0;
                qs[(o0 + 1) * 16 + pix] = a1;
                qs[(o0 + 2) * 16 + pix] = a2;
                qs[(o0 + 3) * 16 + pix] = a3;
            }
        }
        __syncthreads();

        // ---- Phase B2: 5x5 avg-pool (pad 2) within the 4x4 window, 192 ch ----
        if (t < 192) {
            const float4* sr = reinterpret_cast<const float4*>(&qs[t * 16]);
            const float4 r0 = sr[0], r1 = sr[1], r2 = sr[2], r3 = sr[3]; // rows 0..3
            float col[4], tmp0[4], tmp3[4];
            {
                const float c0 = r0.x + r1.x + r2.x + r3.x;
                const float c1 = r0.y + r1.y + r2.y + r3.y;
                const float c2 = r0.z + r1.z + r2.z + r3.z;
                const float c3 = r0.w + r1.w + r2.w + r3.w;
                col[0] = c0; col[1] = c1; col[2] = c2; col[3] = c3;
                tmp0[0] = c0 - r3.x; tmp0[1] = c1 - r3.y; tmp0[2] = c2 - r3.z; tmp0[3] = c3 - r3.w;
                tmp3[0] = c0 - r0.x; tmp3[1] = c1 - r0.y; tmp3[2] = c2 - r0.z; tmp3[3] = c3 - r0.w;
            }
            float4* pr = reinterpret_cast<float4*>(&qs[(192 + t) * 16]);
            const float k25 = 1.f / 25.f;
#pragma unroll
            for (int i = 0; i < 4; ++i) {
                const float* tr = (i == 0) ? tmp0 : ((i == 3) ? tmp3 : col);
                const float hs = tr[0] + tr[1] + tr[2] + tr[3];
                float4 o;
                o.x = (hs - tr[3]) * k25;
                o.y = hs * k25;
                o.z = hs * k25;
                o.w = (hs - tr[0]) * k25;
                pr[i] = o;
            }
        }
        __syncthreads();

        // ---- Phase C: linear attention, 16 groups (8 direct + 8 pooled), 16 lanes/group ----
        {
            const int grp = t >> 4;        // 0..15
            const int l = t & 15;          // pixel
            const int base = (grp < 8) ? (grp * 24 * 16) : ((192 + (grp - 8) * 24) * 16);

            float qd[8], kd[8], vm[8];
#pragma unroll
            for (int d = 0; d < 8; ++d) qd[d] = fmaxf(0.f, qs[base + d * 16 + l]);
#pragma unroll
            for (int d = 0; d < 8; ++d) kd[d] = fmaxf(0.f, qs[base + (8 + d) * 16 + l]);
#pragma unroll
            for (int m = 0; m < 8; ++m) vm[m] = qs[base + (16 + m) * 16 + l];

            float kv[8][9];
#pragma unroll
            for (int d = 0; d < 8; ++d) {
#pragma unroll
                for (int m = 0; m < 8; ++m) kv[d][m] = kd[d] * vm[m];
                kv[d][8] = kd[d];          // v[:,8] == 1 (pad)
            }
            // reduce kv over the 16 lanes of the group (in-wave butterfly)
#pragma unroll
            for (int off = 1; off <= 8; off <<= 1)
#pragma unroll
                for (int d = 0; d < 8; ++d)
#pragma unroll
                    for (int m = 0; m < 9; ++m)
                        kv[d][m] += __shfl_xor(kv[d][m], off, 64);

            float o8 = 0.f;
#pragma unroll
            for (int d = 0; d < 8; ++d) o8 += qd[d] * kv[d][8];
            const float den = 1.f / (o8 + 1e-15f);
#pragma unroll
            for (int m = 0; m < 8; ++m) {
                float om = 0.f;
#pragma unroll
                for (int d = 0; d < 8; ++d) om += qd[d] * kv[d][m];
                att[(grp * 8 + m) * 16 + l] = om * den;   // local c = grp*8+m
            }
        }
        __syncthreads();

        // ---- Phase D: partial proj GEMM for this pass's 128 att channels ----
        {
            const float* wrow = proj_w + (size_t)t * 512;
            const float* wd = wrow + pass * 64;          // direct block
            const float* wp = wrow + 256 + pass * 64;    // pooled block
#pragma unroll 2
            for (int j = 0; j < 64; ++j) {
                const float wdj = wd[j];
                const float wpj = wp[j];
                const float4* ad = reinterpret_cast<const float4*>(&att[j * 16]);        // broadcast
                const float4* ap = reinterpret_cast<const float4*>(&att[(64 + j) * 16]); // broadcast
#pragma unroll
                for (int q4 = 0; q4 < 4; ++q4) {
                    const float4 av = ad[q4];
                    const float4 pv = ap[q4];
                    acc[q4 * 4 + 0] += av.x * wdj + pv.x * wpj;
                    acc[q4 * 4 + 1] += av.y * wdj + pv.y * wpj;
                    acc[q4 * 4 + 2] += av.z * wdj + pv.z * wpj;
                    acc[q4 * 4 + 3] += av.w * wdj + pv.w * wpj;
                }
            }
        }
        __syncthreads();
    }

    // ---- Epilogue: BN + fp32 store ----
    {
        const int oc = t;
        const float inv = bn_g[oc] * __frsqrt_rn(bn_v[oc] + 1e-5f);
        const float bet2 = bn_b[oc] - bn_m[oc] * inv;
#pragma unroll
        for (int i = 0; i < 4; ++i) {
            float4 s4;
            s4.x = acc[i * 4 + 0] * inv + bet2;
            s4.y = acc[i * 4 + 1] * inv + bet2;
            s4.z = acc[i * 4 + 2] * inv + bet2;
            s4.w = acc[i * 4 + 3] * inv + bet2;
            const size_t ea = ((size_t)(b * COUT_ + oc) * H_ + (h0 + i)) * (size_t)W_ + w0;
            *reinterpret_cast<float4*>(y + ea) = s4;    // 16B store, aligned
        }
    }
}

extern "C" void kernel_launch(void* const* d_in, const int* in_sizes, int n_in,
                              void* d_out, int out_size, void* d_ws, size_t ws_size,
                              hipStream_t stream) {
    const float* x      = (const float*)d_in[0];
    const float* qkv_w  = (const float*)d_in[1];
    const float* proj_w = (const float*)d_in[2];
    const float* bn_g   = (const float*)d_in[3];
    const float* bn_b   = (const float*)d_in[4];
    const float* bn_m   = (const float*)d_in[5];
    const float* bn_v   = (const float*)d_in[6];
    float* y = (float*)d_out;
    wmsa_fused<<<dim3(9216), dim3(256), 0, stream>>>(x, qkv_w, proj_w, bn_g, bn_b, bn_m, bn_v, y);
}